// Round 10
// baseline (155.594 us; speedup 1.0000x reference)
//
#include <hip/hip_runtime.h>
#include <math.h>

#define NB     24
#define FBIN   512
#define ROWS   (32*1200)
#define GRID   2048
#define BLK    256
#define WPB    4
#define NWAVES (GRID*WPB)    // 8192 waves; 4-5 rows each
#define SLOTS  20            // stride 80 B -> 16B-aligned b128 reads
#define SCOLP  28            // padded S-column stride (112 B, 16B-aligned)
#define LOG2E  1.44269504f

__device__ __constant__ int   c_off[NB+1] = {0,3,6,9,12,16,20,24,29,34,40,47,55,64,74,86,100,118,140,169,204,246,304,384,512};
__device__ __constant__ float c_k[NB]     = {3,3,3,3,4,4,4,5,5,6,7,8,9,10,12,14,18,22,29,35,42,58,80,128};

#define RDLANE(v,i) __int_as_float(__builtin_amdgcn_readlane(__float_as_int(v), (i)))

__global__ __launch_bounds__(BLK, 8) void pe_main(const float* __restrict__ lm,
                                                  const float* __restrict__ re,
                                                  const float* __restrict__ im,
                                                  const float* __restrict__ S,
                                                  float* __restrict__ partial)
{
    __shared__ float s_slot[WPB][2][NB*SLOTS];  // parity dbuf, 15.4 KB
    __shared__ float s_Scol[NB*SCOLP];          // S column-major, padded
    __shared__ float s_invc[NB];

    const int tid  = threadIdx.x;
    const int w    = tid >> 6;
    const int lane = tid & 63;

    // S -> LDS column-major; 1/(colsum+eps)
    for (int i = tid; i < NB*NB; i += BLK) {
        const int r = i / NB, c = i - r*NB;
        s_Scol[c*SCOLP + r] = S[i];
    }
    __syncthreads();
    if (tid < NB) {
        float cs = 1e-8f;
        for (int i = 0; i < NB; ++i) cs += s_Scol[tid*SCOLP + i];
        s_invc[tid] = 1.0f / cs;
    }
    __syncthreads();

    // zero this wave's two slot buffers (pads stay 0 forever)
    {
        float* sw = &s_slot[w][0][0];
        for (int i = lane; i < 2*NB*SLOTS; i += 64) sw[i] = 0.f;
    }

    // ---- per-lane row-invariant metadata (8 contiguous bins per lane) ----
    const int bin0 = lane * 8;
    int waddr[8];
    unsigned bpk0 = 0, bpk1 = 0;   // band<<2 packed 8-bit, 4 per u32
    unsigned smask = 0;            // bit j: waddr[j]==waddr[j-1]
    float tq[8], a4[8];
    #pragma unroll
    for (int j = 0; j < 8; ++j) {
        const int binj = bin0 + j;
        int b = 0;
        for (int q = 0; q < NB; ++q) if (binj >= c_off[q+1]) b++;
        if (j < 4) bpk0 |= (unsigned)(b << 2) << (8*j);
        else       bpk1 |= (unsigned)(b << 2) << (8*(j-4));
        waddr[j] = b*SLOTS + (lane - (c_off[b] >> 3));
        if (j > 0 && waddr[j] == waddr[j-1]) smask |= 1u << j;
        const float z = (binj + 1) * 0.03125f;
        tq[j] = 3.64f*__builtin_amdgcn_exp2f(-0.8f*__builtin_amdgcn_logf(z + 1e-6f))
              - 6.5f*__builtin_amdgcn_exp2f(-0.6f*LOG2E*(z-3.3f)*(z-3.3f))
              + 1e-3f*z*z*z*z;
        a4[j] = 1.5f / c_k[b];            // 2/denom == rsqrt(a4 * t_bin); weight = a4/57600
    }
    const int cl = (lane < NB) ? lane : NB-1;
    const float invcol = s_invc[cl];
    const float* const Sc = &s_Scol[cl*SCOLP];

    const int gw = blockIdx.x * WPB + w;
    size_t base = (size_t)gw * FBIN + bin0;
    const size_t step = (size_t)NWAVES * FBIN;

    float4 L0 = *(const float4*)(lm + base);
    float4 L1 = *(const float4*)(lm + base + 4);

    float acc = 0.f;
    int par = 0;
    for (int row = gw; row < ROWS; row += NWAVES) {
        const float lmv[8] = {L0.x,L0.y,L0.z,L0.w,L1.x,L1.y,L1.z,L1.w};
        float sp[8];
        #pragma unroll
        for (int j = 0; j < 8; ++j)
            sp[j] = __builtin_amdgcn_exp2f(fminf(lmv[j], 10.f) * LOG2E);

        float* const slot = &s_slot[w][par][0];
        // branchless segmented stores: cumulative rewrite, last write per slot wins
        {
            float ps = sp[0];
            slot[waddr[0]] = ps;
            #pragma unroll
            for (int j = 1; j < 8; ++j) {
                ps = ((smask >> j) & 1u) ? ps + sp[j] : sp[j];
                slot[waddr[j]] = ps;
            }
        }

        // prefetch next row's lm (clamped uniform address)
        const size_t nb = base + ((row + NWAVES < ROWS) ? step : (size_t)0);
        const float4 nL0 = *(const float4*)(lm + nb);
        const float4 nL1 = *(const float4*)(lm + nb + 4);

        asm volatile("s_waitcnt lgkmcnt(0)" ::: "memory");   // own-wave store visibility

        // issue re/im now; consumed after psum+matmul+bpermute (latency covered)
        const float4 R0 = *(const float4*)(re + base);
        const float4 R1 = *(const float4*)(re + base + 4);
        const float4 I0 = *(const float4*)(im + base);
        const float4 I1 = *(const float4*)(im + base + 4);

        // per-band sums (lanes 0-23): 5x b128 from zero-padded slots
        float psum_v = 0.f;
        if (lane < NB) {
            const float4* q = (const float4*)(slot + lane*SLOTS);
            const float4 q0=q[0], q1=q[1], q2=q[2], q3=q[3], q4=q[4];
            psum_v = ((((q0.x+q0.y)+(q0.z+q0.w)) + ((q1.x+q1.y)+(q1.z+q1.w)))
                   +  (((q2.x+q2.y)+(q2.z+q2.w)) + ((q3.x+q3.y)+(q3.z+q3.w))))
                   +   ((q4.x+q4.y)+(q4.z+q4.w));
        }

        // t = (psum@S + eps)*invcol; psum broadcast via readlane, S column from LDS
        float tmine;
        {
            float c0 = 1e-8f, c1 = 0.f, c2 = 0.f, c3 = 0.f;
            #pragma unroll
            for (int i = 0; i < NB; i += 4) {
                const float4 q = *(const float4*)(Sc + i);
                c0 = fmaf(RDLANE(psum_v,i+0), q.x, c0);
                c1 = fmaf(RDLANE(psum_v,i+1), q.y, c1);
                c2 = fmaf(RDLANE(psum_v,i+2), q.z, c2);
                c3 = fmaf(RDLANE(psum_v,i+3), q.w, c3);
            }
            tmine = ((c0+c1)+(c2+c3)) * invcol;
        }

        // broadcast t[band] to all lanes via bpermute (band ids unpacked 8-bit)
        float tb[8];
        #pragma unroll
        for (int j = 0; j < 8; ++j) {
            const unsigned pk = (j < 4) ? bpk0 : bpk1;
            const int b4 = (int)((pk >> (8*(j & 3))) & 0xffu);
            tb[j] = __int_as_float(__builtin_amdgcn_ds_bpermute(b4, __float_as_int(tmine)));
        }

        const float rv[8] = {R0.x,R0.y,R0.z,R0.w,R1.x,R1.y,R1.z,R1.w};
        const float iv[8] = {I0.x,I0.y,I0.z,I0.w,I1.x,I1.y,I1.z,I1.w};
        #pragma unroll
        for (int j = 0; j < 8; ++j) {
            const float t  = fmaxf(tb[j], tq[j]);
            const float s  = __builtin_amdgcn_rsqf(a4[j] * t);
            const float u  = sp[j] * s;
            const float pr = fmaf(fabsf(rv[j]), u, 1.0f);
            const float pi = fmaf(fabsf(iv[j]), u, 1.0f);
            acc = fmaf(__builtin_amdgcn_logf(pr * pi), a4[j], acc);
        }

        par ^= 1;                 // parity dbuf: no tail drain needed
        L0 = nL0; L1 = nL1;
        base += step;
    }

    #pragma unroll
    for (int o = 32; o > 0; o >>= 1) acc += __shfl_xor(acc, o, 64);
    if (lane == 0) partial[gw] = acc * (1.0f/57600.0f);
}

__global__ __launch_bounds__(256) void pe_final(const float* __restrict__ partial,
                                                float* __restrict__ out)
{
    __shared__ double sred[256];
    const int tid = threadIdx.x;
    double s = 0.0;
    for (int i = tid; i < NWAVES; i += 256) s += (double)partial[i];
    sred[tid] = s;
    __syncthreads();
    for (int k = 128; k > 0; k >>= 1) {
        if (tid < k) sred[tid] += sred[tid+k];
        __syncthreads();
    }
    if (tid == 0) out[0] = (float)(1.0 / (sred[0] + 1.0));
}

extern "C" void kernel_launch(void* const* d_in, const int* in_sizes, int n_in,
                              void* d_out, int out_size, void* d_ws, size_t ws_size,
                              hipStream_t stream) {
    const float* lm = (const float*)d_in[0];
    const float* re = (const float*)d_in[1];
    const float* im = (const float*)d_in[2];
    const float* S  = (const float*)d_in[3];
    float* partial = (float*)d_ws;   // NWAVES floats = 32 KB scratch
    pe_main<<<GRID, BLK, 0, stream>>>(lm, re, im, S, partial);
    pe_final<<<1, 256, 0, stream>>>(partial, (float*)d_out);
}

// Round 11
// 54.369 us; speedup vs baseline: 2.8618x; 2.8618x over previous
//
#include <hip/hip_runtime.h>
#include <math.h>

#define NB     24
#define FBIN   512
#define ROWS   (32*1200)
#define GRID   2048
#define BLK    256
#define WPB    4
#define NWAVES (GRID*WPB)    // 8192 waves; 4-5 rows each
#define SLOTS  20            // stride 80 B -> 16B-aligned b128 reads
#define SCOLP  28            // padded S-column stride (112 B, 16B-aligned)
#define LOG2E  1.44269504f

__device__ __constant__ int   c_off[NB+1] = {0,3,6,9,12,16,20,24,29,34,40,47,55,64,74,86,100,118,140,169,204,246,304,384,512};
__device__ __constant__ float c_k[NB]     = {3,3,3,3,4,4,4,5,5,6,7,8,9,10,12,14,18,22,29,35,42,58,80,128};

#define RDLANE(v,i) __int_as_float(__builtin_amdgcn_readlane(__float_as_int(v), (i)))

__global__ __launch_bounds__(BLK) void pe_main(const float* __restrict__ lm,
                                               const float* __restrict__ re,
                                               const float* __restrict__ im,
                                               const float* __restrict__ S,
                                               float* __restrict__ partial)
{
    __shared__ float s_slot[WPB][2][NB*SLOTS];  // parity dbuf, 15.4 KB
    __shared__ float s_Scol[NB*SCOLP];          // S column-major, padded
    __shared__ float s_invc[NB];

    const int tid  = threadIdx.x;
    const int w    = tid >> 6;
    const int lane = tid & 63;

    // S -> LDS column-major; 1/(colsum+eps)
    for (int i = tid; i < NB*NB; i += BLK) {
        const int r = i / NB, c = i - r*NB;
        s_Scol[c*SCOLP + r] = S[i];
    }
    __syncthreads();
    if (tid < NB) {
        float cs = 1e-8f;
        for (int i = 0; i < NB; ++i) cs += s_Scol[tid*SCOLP + i];
        s_invc[tid] = 1.0f / cs;
    }
    __syncthreads();

    // zero this wave's two slot buffers (pads stay 0 forever)
    {
        float* sw = &s_slot[w][0][0];
        for (int i = lane; i < 2*NB*SLOTS; i += 64) sw[i] = 0.f;
    }

    // ---- per-lane row-invariant metadata (8 contiguous bins per lane) ----
    const int bin0 = lane * 8;
    int waddr0 = 0;
    unsigned dpk0 = 0, dpk1 = 0;   // waddr deltas (<=140) packed 8-bit
    unsigned bpk0 = 0, bpk1 = 0;   // band<<2 packed 8-bit
    unsigned smask = 0;            // bit j: same slot as j-1
    float rtq[8], a4[8];
    {
        int wprev = 0;
        #pragma unroll
        for (int j = 0; j < 8; ++j) {
            const int binj = bin0 + j;
            int b = 0;
            for (int q = 0; q < NB; ++q) if (binj >= c_off[q+1]) b++;
            const int wa = b*SLOTS + (lane - (c_off[b] >> 3));
            if (j == 0) waddr0 = wa;
            const unsigned d = (unsigned)(wa - waddr0);
            if (j < 4) { dpk0 |= d << (8*j);      bpk0 |= (unsigned)(b << 2) << (8*j); }
            else       { dpk1 |= d << (8*(j-4));  bpk1 |= (unsigned)(b << 2) << (8*(j-4)); }
            if (j > 0 && wa == wprev) smask |= 1u << j;
            wprev = wa;
            const float z = (binj + 1) * 0.03125f;
            const float tqj = 3.64f*__builtin_amdgcn_exp2f(-0.8f*__builtin_amdgcn_logf(z + 1e-6f))
                            - 6.5f*__builtin_amdgcn_exp2f(-0.6f*LOG2E*(z-3.3f)*(z-3.3f))
                            + 1e-3f*z*z*z*z;
            a4[j] = 1.5f / c_k[b];           // 2/denom == rsqrt(a4 * t); weight = a4/57600
            // rsqrt(a4*max(t,tq)) == min(rsqrt(a4*t), rtq); tq<=0 never binds
            rtq[j] = (tqj > 0.f) ? __builtin_amdgcn_rsqf(a4[j] * tqj) : 3.4e38f;
        }
    }
    const int   cl      = (lane < NB) ? lane : NB-1;
    const float invcol  = s_invc[cl];
    const float abandcl = 1.5f / c_k[cl];
    const float* const Sc = &s_Scol[cl*SCOLP];

    const int gw = blockIdx.x * WPB + w;
    size_t base = (size_t)gw * FBIN + bin0;
    const size_t step = (size_t)NWAVES * FBIN;

    float4 L0 = *(const float4*)(lm + base);
    float4 L1 = *(const float4*)(lm + base + 4);

    float acc = 0.f;
    int par = 0;
    for (int row = gw; row < ROWS; row += NWAVES) {
        const float lmv[8] = {L0.x,L0.y,L0.z,L0.w,L1.x,L1.y,L1.z,L1.w};
        float sp[8];
        #pragma unroll
        for (int j = 0; j < 8; ++j)
            sp[j] = __builtin_amdgcn_exp2f(fminf(lmv[j], 10.f) * LOG2E);

        float* const slot = &s_slot[w][par][0];
        // branchless segmented stores: cumulative rewrite, last write per slot wins
        {
            float ps = sp[0];
            slot[waddr0] = ps;
            #pragma unroll
            for (int j = 1; j < 8; ++j) {
                const unsigned pk = (j < 4) ? dpk0 : dpk1;
                const int wa = waddr0 + (int)((pk >> (8*(j & 3))) & 0xffu);
                ps = ((smask >> j) & 1u) ? ps + sp[j] : sp[j];
                slot[wa] = ps;
            }
        }

        // issue all remaining global loads BEFORE the LDS drain: latency rides the band phase
        const size_t nb = base + ((row + NWAVES < ROWS) ? step : (size_t)0);
        const float4 nL0 = *(const float4*)(lm + nb);
        const float4 nL1 = *(const float4*)(lm + nb + 4);
        const float4 R0 = *(const float4*)(re + base);
        const float4 R1 = *(const float4*)(re + base + 4);
        const float4 I0 = *(const float4*)(im + base);
        const float4 I1 = *(const float4*)(im + base + 4);

        asm volatile("s_waitcnt lgkmcnt(0)" ::: "memory");   // own-wave store visibility

        // per-band sums: all lanes, clamped to band cl (lanes>=24 broadcast band 23: free)
        float psum_v;
        {
            const float4* q = (const float4*)(slot + cl*SLOTS);
            const float4 q0=q[0], q1=q[1], q2=q[2], q3=q[3], q4=q[4];
            psum_v = ((((q0.x+q0.y)+(q0.z+q0.w)) + ((q1.x+q1.y)+(q1.z+q1.w)))
                   +  (((q2.x+q2.y)+(q2.z+q2.w)) + ((q3.x+q3.y)+(q3.z+q3.w))))
                   +   ((q4.x+q4.y)+(q4.z+q4.w));
        }

        // t = (psum@S + eps)*invcol; psum broadcast via readlane, S column from LDS
        // then vb = rsqrt(a4_band * t) once per band (lane space)
        float vb;
        {
            float c0 = 1e-8f, c1 = 0.f, c2 = 0.f, c3 = 0.f;
            #pragma unroll
            for (int i = 0; i < NB; i += 4) {
                const float4 q = *(const float4*)(Sc + i);
                c0 = fmaf(RDLANE(psum_v,i+0), q.x, c0);
                c1 = fmaf(RDLANE(psum_v,i+1), q.y, c1);
                c2 = fmaf(RDLANE(psum_v,i+2), q.z, c2);
                c3 = fmaf(RDLANE(psum_v,i+3), q.w, c3);
            }
            const float tmine = ((c0+c1)+(c2+c3)) * invcol;
            vb = __builtin_amdgcn_rsqf(abandcl * tmine);
        }

        // broadcast vb[band] to all lanes via bpermute
        float vbb[8];
        #pragma unroll
        for (int j = 0; j < 8; ++j) {
            const unsigned pk = (j < 4) ? bpk0 : bpk1;
            const int b4 = (int)((pk >> (8*(j & 3))) & 0xffu);
            vbb[j] = __int_as_float(__builtin_amdgcn_ds_bpermute(b4, __float_as_int(vb)));
        }

        const float rv[8] = {R0.x,R0.y,R0.z,R0.w,R1.x,R1.y,R1.z,R1.w};
        const float iv[8] = {I0.x,I0.y,I0.z,I0.w,I1.x,I1.y,I1.z,I1.w};
        #pragma unroll
        for (int j = 0; j < 8; ++j) {
            const float u  = sp[j] * fminf(vbb[j], rtq[j]);   // == sp*rsqrt(a4*max(t,tq))
            const float pr = fmaf(fabsf(rv[j]), u, 1.0f);
            const float pi = fmaf(fabsf(iv[j]), u, 1.0f);
            acc = fmaf(__builtin_amdgcn_logf(pr * pi), a4[j], acc);
        }

        par ^= 1;                 // parity dbuf: no tail drain needed
        L0 = nL0; L1 = nL1;
        base += step;
    }

    #pragma unroll
    for (int o = 32; o > 0; o >>= 1) acc += __shfl_xor(acc, o, 64);
    if (lane == 0) partial[gw] = acc * (1.0f/57600.0f);
}

__global__ __launch_bounds__(256) void pe_final(const float* __restrict__ partial,
                                                float* __restrict__ out)
{
    __shared__ double sred[256];
    const int tid = threadIdx.x;
    double s = 0.0;
    for (int i = tid; i < NWAVES; i += 256) s += (double)partial[i];
    sred[tid] = s;
    __syncthreads();
    for (int k = 128; k > 0; k >>= 1) {
        if (tid < k) sred[tid] += sred[tid+k];
        __syncthreads();
    }
    if (tid == 0) out[0] = (float)(1.0 / (sred[0] + 1.0));
}

extern "C" void kernel_launch(void* const* d_in, const int* in_sizes, int n_in,
                              void* d_out, int out_size, void* d_ws, size_t ws_size,
                              hipStream_t stream) {
    const float* lm = (const float*)d_in[0];
    const float* re = (const float*)d_in[1];
    const float* im = (const float*)d_in[2];
    const float* S  = (const float*)d_in[3];
    float* partial = (float*)d_ws;   // NWAVES floats = 32 KB scratch
    pe_main<<<GRID, BLK, 0, stream>>>(lm, re, im, S, partial);
    pe_final<<<1, 256, 0, stream>>>(partial, (float*)d_out);
}

// Round 12
// 53.730 us; speedup vs baseline: 2.8958x; 1.0119x over previous
//
#include <hip/hip_runtime.h>
#include <math.h>

#define NB     24
#define FBIN   512
#define ROWS   (32*1200)
#define GRID   2048
#define BLK    256
#define WPB    4
#define NWAVES (GRID*WPB)    // 8192 waves; 4-5 rows each
#define SLOTS  20            // stride 80 B -> 16B-aligned b128 reads
#define SCOLP  28            // padded S-column stride (112 B, 16B-aligned)
#define LOG2E  1.44269504f

__device__ __constant__ int   c_off[NB+1] = {0,3,6,9,12,16,20,24,29,34,40,47,55,64,74,86,100,118,140,169,204,246,304,384,512};
__device__ __constant__ float c_k[NB]     = {3,3,3,3,4,4,4,5,5,6,7,8,9,10,12,14,18,22,29,35,42,58,80,128};

#define RDLANE(v,i) __int_as_float(__builtin_amdgcn_readlane(__float_as_int(v), (i)))

__global__ __launch_bounds__(BLK) void pe_main(const float* __restrict__ lm,
                                               const float* __restrict__ re,
                                               const float* __restrict__ im,
                                               const float* __restrict__ S,
                                               float* __restrict__ partial)
{
    __shared__ float          s_slot[WPB][NB*SLOTS];  // 7.68 KB
    __shared__ float          s_Scol[NB*SCOLP];       // S column-major, padded
    __shared__ float          s_invc[NB];
    __shared__ unsigned short s_meta[FBIN];           // band | (chunk0<<8)
    __shared__ float          s_rtq[FBIN];            // rsqrt(a4*tq), INF if tq<=0

    const int tid  = threadIdx.x;
    const int w    = tid >> 6;
    const int lane = tid & 63;

    const int gw = blockIdx.x * WPB + w;
    const int bin0 = lane * 8;
    size_t base = (size_t)gw * FBIN + bin0;
    const size_t step = (size_t)NWAVES * FBIN;

    // issue first row's lm load before the prologue (latency hidden under setup)
    float4 L0 = *(const float4*)(lm + base);
    float4 L1 = *(const float4*)(lm + base + 4);

    // ---- block-cooperative tables: 2 bins per thread ----
    #pragma unroll
    for (int u = 0; u < 2; ++u) {
        const int bin = tid + u*BLK;
        int b = 0;
        for (int q = 0; q < NB; ++q) if (bin >= c_off[q+1]) b++;
        s_meta[bin] = (unsigned short)(b | ((c_off[b] >> 3) << 8));
        const float z = (bin + 1) * 0.03125f;
        const float tq = 3.64f * powf(z + 1e-6f, -0.8f)
                       - 6.5f * expf(-0.6f * (z-3.3f) * (z-3.3f))
                       + 1e-3f * z*z*z*z;
        const float a4b = 1.5f / c_k[b];
        s_rtq[bin] = (tq > 0.f) ? __builtin_amdgcn_rsqf(a4b * tq) : 3.4e38f;
    }
    // S -> LDS column-major (padded stride)
    for (int i = tid; i < NB*NB; i += BLK) {
        const int r = i / NB, c = i - r*NB;
        s_Scol[c*SCOLP + r] = S[i];
    }
    // zero this wave's slot buffer (pads stay 0 forever)
    for (int i = lane; i < NB*SLOTS; i += 64) s_slot[w][i] = 0.f;
    __syncthreads();
    if (tid < NB) {
        float cs = 1e-8f;
        for (int i = 0; i < NB; ++i) cs += s_Scol[tid*SCOLP + i];
        s_invc[tid] = 1.0f / cs;
    }
    __syncthreads();

    // ---- per-lane metadata from tables (1x b128 + 1x b64 LDS read) ----
    int waddr[8], band4[8];
    unsigned smask = 0;
    float a4[8], rtq[8];
    {
        const ushort4 m0 = *(const ushort4*)(s_meta + bin0);
        const ushort4 m1 = *(const ushort4*)(s_meta + bin0 + 4);
        const unsigned short mv[8] = {m0.x,m0.y,m0.z,m0.w,m1.x,m1.y,m1.z,m1.w};
        const float4 t0 = *(const float4*)(s_rtq + bin0);
        const float4 t1 = *(const float4*)(s_rtq + bin0 + 4);
        const float tv[8] = {t0.x,t0.y,t0.z,t0.w,t1.x,t1.y,t1.z,t1.w};
        #pragma unroll
        for (int j = 0; j < 8; ++j) {
            const int b = mv[j] & 0xff;
            band4[j] = b << 2;
            waddr[j] = b*SLOTS + (lane - (mv[j] >> 8));
            if (j > 0 && waddr[j] == waddr[j-1]) smask |= 1u << j;
            a4[j]  = 1.5f / c_k[b];
            rtq[j] = tv[j];
        }
    }
    const int   cl      = (lane < NB) ? lane : NB-1;
    const float invcol  = s_invc[cl];
    const float abandcl = 1.5f / c_k[cl];
    const float* const Sc = &s_Scol[cl*SCOLP];
    float* const slot = &s_slot[w][0];

    float acc = 0.f;
    for (int row = gw; row < ROWS; row += NWAVES) {
        // re/im issued at iteration top; consumed only in the last phase
        const float4 R0 = *(const float4*)(re + base);
        const float4 R1 = *(const float4*)(re + base + 4);
        const float4 I0 = *(const float4*)(im + base);
        const float4 I1 = *(const float4*)(im + base + 4);

        const float lmv[8] = {L0.x,L0.y,L0.z,L0.w,L1.x,L1.y,L1.z,L1.w};
        float sp[8];
        #pragma unroll
        for (int j = 0; j < 8; ++j)
            sp[j] = __builtin_amdgcn_exp2f(fminf(lmv[j], 10.f) * LOG2E);

        // branchless segmented stores: cumulative rewrite, last write per slot wins
        {
            float ps = sp[0];
            slot[waddr[0]] = ps;
            #pragma unroll
            for (int j = 1; j < 8; ++j) {
                ps = ((smask >> j) & 1u) ? ps + sp[j] : sp[j];
                slot[waddr[j]] = ps;
            }
        }

        // prefetch next row's lm (clamped uniform address, branchless)
        const size_t nb = base + ((row + NWAVES < ROWS) ? step : (size_t)0);
        const float4 nL0 = *(const float4*)(lm + nb);
        const float4 nL1 = *(const float4*)(lm + nb + 4);

        asm volatile("s_waitcnt lgkmcnt(0)" ::: "memory");   // own-wave store visibility

        // per-band sums (lanes 0-23): 5x b128 from zero-padded slots
        float psum_v = 0.f;
        if (lane < NB) {
            const float4* q = (const float4*)(slot + lane*SLOTS);
            const float4 q0=q[0], q1=q[1], q2=q[2], q3=q[3], q4=q[4];
            psum_v = ((((q0.x+q0.y)+(q0.z+q0.w)) + ((q1.x+q1.y)+(q1.z+q1.w)))
                   +  (((q2.x+q2.y)+(q2.z+q2.w)) + ((q3.x+q3.y)+(q3.z+q3.w))))
                   +   ((q4.x+q4.y)+(q4.z+q4.w));
        }

        // t = (psum@S + eps)*invcol; psum broadcast via readlane, S column from LDS;
        // one rsq per band: vb = rsqrt(a4_band * t)
        float vb;
        {
            float c0 = 1e-8f, c1 = 0.f, c2 = 0.f, c3 = 0.f;
            #pragma unroll
            for (int i = 0; i < NB; i += 4) {
                const float4 q = *(const float4*)(Sc + i);
                c0 = fmaf(RDLANE(psum_v,i+0), q.x, c0);
                c1 = fmaf(RDLANE(psum_v,i+1), q.y, c1);
                c2 = fmaf(RDLANE(psum_v,i+2), q.z, c2);
                c3 = fmaf(RDLANE(psum_v,i+3), q.w, c3);
            }
            const float tmine = ((c0+c1)+(c2+c3)) * invcol;
            vb = __builtin_amdgcn_rsqf(abandcl * tmine);
        }

        // broadcast vb[band] to all lanes via bpermute
        float vbb[8];
        #pragma unroll
        for (int j = 0; j < 8; ++j)
            vbb[j] = __int_as_float(__builtin_amdgcn_ds_bpermute(band4[j], __float_as_int(vb)));

        const float rv[8] = {R0.x,R0.y,R0.z,R0.w,R1.x,R1.y,R1.z,R1.w};
        const float iv[8] = {I0.x,I0.y,I0.z,I0.w,I1.x,I1.y,I1.z,I1.w};
        #pragma unroll
        for (int j = 0; j < 8; ++j) {
            const float u  = sp[j] * fminf(vbb[j], rtq[j]);   // == sp*rsqrt(a4*max(t,tq))
            const float pr = fmaf(fabsf(rv[j]), u, 1.0f);
            const float pi = fmaf(fabsf(iv[j]), u, 1.0f);
            acc = fmaf(__builtin_amdgcn_logf(pr * pi), a4[j], acc);
        }

        asm volatile("s_waitcnt lgkmcnt(0)" ::: "memory");   // drain before slot reuse

        L0 = nL0; L1 = nL1;
        base += step;
    }

    #pragma unroll
    for (int o = 32; o > 0; o >>= 1) acc += __shfl_xor(acc, o, 64);
    if (lane == 0) partial[gw] = acc * (1.0f/57600.0f);
}

__global__ __launch_bounds__(256) void pe_final(const float* __restrict__ partial,
                                                float* __restrict__ out)
{
    __shared__ double sred[256];
    const int tid = threadIdx.x;
    double s = 0.0;
    for (int i = tid; i < NWAVES; i += 256) s += (double)partial[i];
    sred[tid] = s;
    __syncthreads();
    for (int k = 128; k > 0; k >>= 1) {
        if (tid < k) sred[tid] += sred[tid+k];
        __syncthreads();
    }
    if (tid == 0) out[0] = (float)(1.0 / (sred[0] + 1.0));
}

extern "C" void kernel_launch(void* const* d_in, const int* in_sizes, int n_in,
                              void* d_out, int out_size, void* d_ws, size_t ws_size,
                              hipStream_t stream) {
    const float* lm = (const float*)d_in[0];
    const float* re = (const float*)d_in[1];
    const float* im = (const float*)d_in[2];
    const float* S  = (const float*)d_in[3];
    float* partial = (float*)d_ws;   // NWAVES floats = 32 KB scratch
    pe_main<<<GRID, BLK, 0, stream>>>(lm, re, im, S, partial);
    pe_final<<<1, 256, 0, stream>>>(partial, (float*)d_out);
}

// Round 13
// 51.780 us; speedup vs baseline: 3.0049x; 1.0377x over previous
//
#include <hip/hip_runtime.h>
#include <math.h>

#define NB     24
#define FBIN   512
#define ROWS   (32*1200)
#define GRID   2048
#define BLK    256
#define WPB    4
#define NWAVES (GRID*WPB)    // 8192 waves; 4-5 rows each
#define SLOTS  20            // stride 80 B -> 16B-aligned b128 reads
#define LOG2E  1.44269504f

__device__ __constant__ int   c_off[NB+1] = {0,3,6,9,12,16,20,24,29,34,40,47,55,64,74,86,100,118,140,169,204,246,304,384,512};
__device__ __constant__ float c_k[NB]     = {3,3,3,3,4,4,4,5,5,6,7,8,9,10,12,14,18,22,29,35,42,58,80,128};

#define RDLANE(v,i) __int_as_float(__builtin_amdgcn_readlane(__float_as_int(v), (i)))

__global__ __launch_bounds__(BLK) void pe_main(const float* __restrict__ lm,
                                               const float* __restrict__ re,
                                               const float* __restrict__ im,
                                               const float* __restrict__ S,
                                               float* __restrict__ partial)
{
    __shared__ float s_slot[WPB][2][NB*SLOTS];   // parity dbuf, 15.4 KB

    const int tid  = threadIdx.x;
    const int w    = tid >> 6;
    const int lane = tid & 63;

    // zero this wave's two slot buffers (pads stay 0 forever)
    {
        float* sw = &s_slot[w][0][0];
        for (int i = lane; i < 2*NB*SLOTS; i += 64) sw[i] = 0.f;
    }

    // ---- per-lane row-invariant metadata (8 contiguous bins per lane) ----
    const int bin0 = lane * 8;
    int waddr[8], band4[8];
    unsigned smask = 0;
    float rtq[8], a4[8];
    #pragma unroll
    for (int j = 0; j < 8; ++j) {
        const int binj = bin0 + j;
        int b = 0;
        for (int q = 0; q < NB; ++q) if (binj >= c_off[q+1]) b++;
        band4[j] = b << 2;
        waddr[j] = b*SLOTS + (lane - (c_off[b] >> 3));
        if (j > 0 && waddr[j] == waddr[j-1]) smask |= 1u << j;
        const float z = (binj + 1) * 0.03125f;
        const float tqj = 3.64f*__builtin_amdgcn_exp2f(-0.8f*__builtin_amdgcn_logf(z + 1e-6f))
                        - 6.5f*__builtin_amdgcn_exp2f(-0.6f*LOG2E*(z-3.3f)*(z-3.3f))
                        + 1e-3f*z*z*z*z;
        a4[j] = 1.5f / c_k[b];            // 2/denom == rsqrt(a4 * t); weight = a4/57600
        // rsqrt(a4*max(t,tq)) == min(rsqrt(a4*t), rtq); tq<=0 never binds
        rtq[j] = (tqj > 0.f) ? __builtin_amdgcn_rsqf(a4[j] * tqj) : 3.4e38f;
    }

    // S column for my band (lanes 0-23) + 1/(colsum+eps), in registers (R8-proven)
    const int cl = (lane < NB) ? lane : NB-1;
    float Sreg[NB];
    float colsum = 1e-8f;
    #pragma unroll
    for (int i = 0; i < NB; ++i) { Sreg[i] = S[i*NB + cl]; colsum += Sreg[i]; }
    const float invcol  = 1.0f / colsum;
    const float abandcl = 1.5f / c_k[cl];

    const int gw = blockIdx.x * WPB + w;
    size_t base = (size_t)gw * FBIN + bin0;
    const size_t step = (size_t)NWAVES * FBIN;

    // preload row 0 of ALL THREE streams
    float4 L0 = *(const float4*)(lm + base), L1 = *(const float4*)(lm + base + 4);
    float4 R0 = *(const float4*)(re + base), R1 = *(const float4*)(re + base + 4);
    float4 I0 = *(const float4*)(im + base), I1 = *(const float4*)(im + base + 4);

    float acc = 0.f;
    int par = 0;
    for (int row = gw; row < ROWS; row += NWAVES) {
        const float lmv[8] = {L0.x,L0.y,L0.z,L0.w,L1.x,L1.y,L1.z,L1.w};
        float sp[8];
        #pragma unroll
        for (int j = 0; j < 8; ++j)
            sp[j] = __builtin_amdgcn_exp2f(fminf(lmv[j], 10.f) * LOG2E);

        float* const slot = &s_slot[w][par][0];
        // branchless segmented stores: cumulative rewrite, last write per slot wins
        {
            float ps = sp[0];
            slot[waddr[0]] = ps;
            #pragma unroll
            for (int j = 1; j < 8; ++j) {
                ps = ((smask >> j) & 1u) ? ps + sp[j] : sp[j];
                slot[waddr[j]] = ps;
            }
        }

        // FULL next-row prefetch (all 3 streams), issued before the LDS drain;
        // consumed one full iteration later (~800 cyc of cover)
        const size_t nb = base + ((row + NWAVES < ROWS) ? step : (size_t)0);
        const float4 nL0 = *(const float4*)(lm + nb), nL1 = *(const float4*)(lm + nb + 4);
        const float4 nR0 = *(const float4*)(re + nb), nR1 = *(const float4*)(re + nb + 4);
        const float4 nI0 = *(const float4*)(im + nb), nI1 = *(const float4*)(im + nb + 4);

        asm volatile("s_waitcnt lgkmcnt(0)" ::: "memory");   // own-wave store visibility

        // per-band sums (lanes 0-23): 5x b128 from zero-padded slots
        float psum_v = 0.f;
        if (lane < NB) {
            const float4* q = (const float4*)(slot + lane*SLOTS);
            const float4 q0=q[0], q1=q[1], q2=q[2], q3=q[3], q4=q[4];
            psum_v = ((((q0.x+q0.y)+(q0.z+q0.w)) + ((q1.x+q1.y)+(q1.z+q1.w)))
                   +  (((q2.x+q2.y)+(q2.z+q2.w)) + ((q3.x+q3.y)+(q3.z+q3.w))))
                   +   ((q4.x+q4.y)+(q4.z+q4.w));
        }

        // t = (psum@S + eps)*invcol; psum broadcast via readlane, S from registers;
        // one rsq per band: vb = rsqrt(a4_band * t)
        float vb;
        {
            float c0 = 1e-8f, c1 = 0.f, c2 = 0.f, c3 = 0.f;
            #pragma unroll
            for (int i = 0; i < NB; i += 4) {
                c0 = fmaf(RDLANE(psum_v,i+0), Sreg[i+0], c0);
                c1 = fmaf(RDLANE(psum_v,i+1), Sreg[i+1], c1);
                c2 = fmaf(RDLANE(psum_v,i+2), Sreg[i+2], c2);
                c3 = fmaf(RDLANE(psum_v,i+3), Sreg[i+3], c3);
            }
            const float tmine = ((c0+c1)+(c2+c3)) * invcol;
            vb = __builtin_amdgcn_rsqf(abandcl * tmine);
        }

        // broadcast vb[band] to all lanes via bpermute
        float vbb[8];
        #pragma unroll
        for (int j = 0; j < 8; ++j)
            vbb[j] = __int_as_float(__builtin_amdgcn_ds_bpermute(band4[j], __float_as_int(vb)));

        const float rv[8] = {R0.x,R0.y,R0.z,R0.w,R1.x,R1.y,R1.z,R1.w};
        const float iv[8] = {I0.x,I0.y,I0.z,I0.w,I1.x,I1.y,I1.z,I1.w};
        #pragma unroll
        for (int j = 0; j < 8; ++j) {
            const float u  = sp[j] * fminf(vbb[j], rtq[j]);   // == sp*rsqrt(a4*max(t,tq))
            const float pr = fmaf(fabsf(rv[j]), u, 1.0f);
            const float pi = fmaf(fabsf(iv[j]), u, 1.0f);
            acc = fmaf(__builtin_amdgcn_logf(pr * pi), a4[j], acc);
        }

        par ^= 1;                 // parity dbuf: no tail drain needed
        L0 = nL0; L1 = nL1; R0 = nR0; R1 = nR1; I0 = nI0; I1 = nI1;
        base += step;
    }

    #pragma unroll
    for (int o = 32; o > 0; o >>= 1) acc += __shfl_xor(acc, o, 64);
    if (lane == 0) partial[gw] = acc * (1.0f/57600.0f);
}

__global__ __launch_bounds__(256) void pe_final(const float* __restrict__ partial,
                                                float* __restrict__ out)
{
    __shared__ double sred[256];
    const int tid = threadIdx.x;
    double s = 0.0;
    for (int i = tid; i < NWAVES; i += 256) s += (double)partial[i];
    sred[tid] = s;
    __syncthreads();
    for (int k = 128; k > 0; k >>= 1) {
        if (tid < k) sred[tid] += sred[tid+k];
        __syncthreads();
    }
    if (tid == 0) out[0] = (float)(1.0 / (sred[0] + 1.0));
}

extern "C" void kernel_launch(void* const* d_in, const int* in_sizes, int n_in,
                              void* d_out, int out_size, void* d_ws, size_t ws_size,
                              hipStream_t stream) {
    const float* lm = (const float*)d_in[0];
    const float* re = (const float*)d_in[1];
    const float* im = (const float*)d_in[2];
    const float* S  = (const float*)d_in[3];
    float* partial = (float*)d_ws;   // NWAVES floats = 32 KB scratch
    pe_main<<<GRID, BLK, 0, stream>>>(lm, re, im, S, partial);
    pe_final<<<1, 256, 0, stream>>>(partial, (float*)d_out);
}